// Round 2
// baseline (1052.054 us; speedup 1.0000x reference)
//
#include <hip/hip_runtime.h>

#define B_    2
#define S_    2048
#define H_    32
#define KVH_  8
#define D_    128
#define QB    64
#define KB    64
#define NREP  (H_ / KVH_)
#define SCALE 0.08838834764831845f  // 128^-0.5

typedef short  short8 __attribute__((ext_vector_type(8)));
typedef float  f32x4  __attribute__((ext_vector_type(4)));

__device__ inline unsigned short f2bf(float f) {
    unsigned int u = __float_as_uint(f);
    u += 0x7fffu + ((u >> 16) & 1u);
    return (unsigned short)(u >> 16);
}

// ---- pre-pass 1: K fp32 -> bf16 (layout unchanged: [b][s][kvh*D+d]) ----
__global__ void kconv_kernel(const float* __restrict__ k, unsigned short* __restrict__ ko) {
    const size_t i = ((size_t)blockIdx.x * 256 + threadIdx.x) * 4;
    const float4 x = *(const float4*)(k + i);
    ushort4 w;
    w.x = f2bf(x.x); w.y = f2bf(x.y); w.z = f2bf(x.z); w.w = f2bf(x.w);
    *(ushort4*)(ko + i) = w;
}

// ---- pre-pass 2: V fp32 [b][s][kvh][d] -> bf16 transposed VT [b][kvh][d][s] ----
__global__ void vtrans_kernel(const float* __restrict__ v, unsigned short* __restrict__ vt) {
    __shared__ unsigned short tile[32][33];
    const int r = threadIdx.x >> 5, c = threadIdx.x & 31;
    const int s0 = blockIdx.x * 32, d0 = blockIdx.y * 32;
    const int b = blockIdx.z >> 3, kvh = blockIdx.z & 7;
    #pragma unroll
    for (int i = 0; i < 4; ++i) {
        const int s = s0 + r + i * 8;
        const float x = v[((size_t)(b * S_ + s)) * (KVH_ * D_) + kvh * D_ + d0 + c];
        tile[c][r + i * 8] = f2bf(x);
    }
    __syncthreads();
    #pragma unroll
    for (int i = 0; i < 4; ++i) {
        vt[((size_t)((b * KVH_ + kvh) * D_ + d0 + r + i * 8)) * S_ + s0 + c] =
            tile[r + i * 8][c];
    }
}

// ---- main: flash attention, no __syncthreads in the K-loop ----
// Each wave: 16 q-rows. K/VT B-fragments read directly from global (L1/L2-cached).
// Only LDS use: wave-private P round-trip (C-layout -> A-layout), ordered by lgkmcnt.
__global__ __launch_bounds__(256, 4) void fa2_kernel(
    const float* __restrict__ q, const unsigned short* __restrict__ kc,
    const unsigned short* __restrict__ vt, float* __restrict__ out) {

#define P_STRIDE 72
    __shared__ unsigned short Psh[QB * P_STRIDE];  // 9216 B, wave-private by row range

    const int t    = threadIdx.x;
    const int wave = t >> 6;
    const int lane = t & 63;
    const int m16  = lane & 15;
    const int quad = lane >> 4;

    const int qt  = (S_ / QB - 1) - blockIdx.x;  // heavy tiles first
    const int bh  = blockIdx.y;
    const int b   = bh / H_;
    const int h   = bh % H_;
    const int kvh = h / NREP;
    const int qbase = qt * QB;
    const int qrow  = qbase + wave * 16 + m16;   // this lane's A-fragment row

    // ---- Q A-fragments straight from global fp32 (once per block) ----
    short8 qf[4];
    {
        const float* qp = q + (size_t)(b * S_ + qrow) * (H_ * D_) + h * D_;
        #pragma unroll
        for (int c = 0; c < 4; ++c) {
            const float4 x0 = *(const float4*)(qp + c * 32 + quad * 8);
            const float4 x1 = *(const float4*)(qp + c * 32 + quad * 8 + 4);
            short8 f;
            f[0] = (short)f2bf(x0.x); f[1] = (short)f2bf(x0.y);
            f[2] = (short)f2bf(x0.z); f[3] = (short)f2bf(x0.w);
            f[4] = (short)f2bf(x1.x); f[5] = (short)f2bf(x1.y);
            f[6] = (short)f2bf(x1.z); f[7] = (short)f2bf(x1.w);
            qf[c] = f;
        }
    }

    f32x4 o[8];
    #pragma unroll
    for (int i = 0; i < 8; ++i) o[i] = (f32x4){0.f, 0.f, 0.f, 0.f};
    float m_i[4], l_i[4];
    #pragma unroll
    for (int r = 0; r < 4; ++r) { m_i[r] = -INFINITY; l_i[r] = 0.f; }

    const unsigned short* kp = kc + (size_t)b * S_ * (KVH_ * D_) + kvh * D_;
    const unsigned short* vp = vt + (size_t)(b * KVH_ + kvh) * D_ * S_;

    for (int kt = 0; kt <= qt; ++kt) {
        const int kb = kt * KB;

        // ---- S = Q K^T: B-frags direct from global bf16 K ----
        f32x4 sa[4];
        #pragma unroll
        for (int nt = 0; nt < 4; ++nt) sa[nt] = (f32x4){0.f, 0.f, 0.f, 0.f};
        #pragma unroll
        for (int c = 0; c < 4; ++c) {
            short8 kf[4];
            #pragma unroll
            for (int nt = 0; nt < 4; ++nt)
                kf[nt] = *(const short8*)
                    (kp + (size_t)(kb + nt * 16 + m16) * (KVH_ * D_) + c * 32 + quad * 8);
            #pragma unroll
            for (int nt = 0; nt < 4; ++nt)
                sa[nt] = __builtin_amdgcn_mfma_f32_16x16x32_bf16(qf[c], kf[nt], sa[nt], 0, 0, 0);
        }

        // ---- scale + causal mask ----
        const bool diag = (kt == qt);
        float p[4][4];
        #pragma unroll
        for (int nt = 0; nt < 4; ++nt) {
            #pragma unroll
            for (int r = 0; r < 4; ++r) {
                float sv = sa[nt][r] * SCALE;
                if (diag) {
                    const int rowg = qbase + wave * 16 + quad * 4 + r;
                    const int colg = kb + nt * 16 + m16;
                    if (colg > rowg) sv = -INFINITY;
                }
                p[nt][r] = sv;
            }
        }

        // ---- online softmax (reduce across the quad-row's 16 lanes) ----
        float alpha[4];
        #pragma unroll
        for (int r = 0; r < 4; ++r) {
            float mv = fmaxf(fmaxf(p[0][r], p[1][r]), fmaxf(p[2][r], p[3][r]));
            mv = fmaxf(mv, __shfl_xor(mv, 1));
            mv = fmaxf(mv, __shfl_xor(mv, 2));
            mv = fmaxf(mv, __shfl_xor(mv, 4));
            mv = fmaxf(mv, __shfl_xor(mv, 8));
            const float mnew = fmaxf(m_i[r], mv);
            alpha[r] = __expf(m_i[r] - mnew);
            m_i[r] = mnew;
            float rs = 0.f;
            #pragma unroll
            for (int nt = 0; nt < 4; ++nt) {
                const float e = __expf(p[nt][r] - mnew);
                p[nt][r] = e;
                rs += e;
            }
            rs += __shfl_xor(rs, 1);
            rs += __shfl_xor(rs, 2);
            rs += __shfl_xor(rs, 4);
            rs += __shfl_xor(rs, 8);
            l_i[r] = l_i[r] * alpha[r] + rs;
        }

        // ---- P: C-layout -> LDS (wave-private rows) ----
        #pragma unroll
        for (int nt = 0; nt < 4; ++nt)
            #pragma unroll
            for (int r = 0; r < 4; ++r)
                Psh[(wave * 16 + quad * 4 + r) * P_STRIDE + nt * 16 + m16] = f2bf(p[nt][r]);

        // rescale O while the P writes drain
        #pragma unroll
        for (int dn = 0; dn < 8; ++dn)
            #pragma unroll
            for (int r = 0; r < 4; ++r)
                o[dn][r] *= alpha[r];

        // same-wave LDS RAW: drain writes, then read A-fragments
        asm volatile("s_waitcnt lgkmcnt(0)" ::: "memory");
        const short8 pf0 = *(const short8*)&Psh[(wave * 16 + m16) * P_STRIDE + quad * 8];
        const short8 pf1 = *(const short8*)&Psh[(wave * 16 + m16) * P_STRIDE + 32 + quad * 8];

        // ---- O += P V: VT B-frags direct from global ----
        #pragma unroll
        for (int c2 = 0; c2 < 2; ++c2) {
            const short8 pf = c2 ? pf1 : pf0;
            #pragma unroll
            for (int dn = 0; dn < 8; ++dn) {
                const short8 vf = *(const short8*)
                    (vp + (size_t)(dn * 16 + m16) * S_ + kb + c2 * 32 + quad * 8);
                o[dn] = __builtin_amdgcn_mfma_f32_16x16x32_bf16(pf, vf, o[dn], 0, 0, 0);
            }
        }
    }

    // ---- epilogue ----
    float inv[4];
    #pragma unroll
    for (int r = 0; r < 4; ++r) inv[r] = 1.f / l_i[r];
    float* og = out + (size_t)(b * S_ + qbase) * (H_ * D_) + h * D_;
    #pragma unroll
    for (int dn = 0; dn < 8; ++dn) {
        #pragma unroll
        for (int r = 0; r < 4; ++r) {
            const int row = wave * 16 + quad * 4 + r;
            og[(size_t)row * (H_ * D_) + dn * 16 + m16] = o[dn][r] * inv[r];
        }
    }
#undef P_STRIDE
}

extern "C" void kernel_launch(void* const* d_in, const int* in_sizes, int n_in,
                              void* d_out, int out_size, void* d_ws, size_t ws_size,
                              hipStream_t stream) {
    const float* q = (const float*)d_in[0];
    const float* k = (const float*)d_in[1];
    const float* v = (const float*)d_in[2];
    float* out = (float*)d_out;

    unsigned short* kc = (unsigned short*)d_ws;                        // 8.4 MB
    unsigned short* vt = (unsigned short*)d_ws + (size_t)B_ * S_ * KVH_ * D_;  // 8.4 MB

    // K -> bf16 (elementwise): 2*2048*1024 elems / 4 per thread / 256 = 4096 blocks
    kconv_kernel<<<dim3(4096), dim3(256), 0, stream>>>(k, kc);
    // V -> bf16 transposed [b][kvh][d][s]
    vtrans_kernel<<<dim3(S_ / 32, D_ / 32, B_ * KVH_), dim3(256), 0, stream>>>(v, vt);
    // main
    fa2_kernel<<<dim3(S_ / QB, B_ * H_), dim3(256), 0, stream>>>(q, kc, vt, out);
}

// Round 3
// 430.323 us; speedup vs baseline: 2.4448x; 2.4448x over previous
//
#include <hip/hip_runtime.h>

#define B_    2
#define S_    2048
#define H_    32
#define KVH_  8
#define D_    128
#define QB    64
#define KB    64
#define NT_   (S_ / KB)
#define NREP  (H_ / KVH_)
#define SCALE 0.08838834764831845f  // 128^-0.5

typedef short  short8 __attribute__((ext_vector_type(8)));
typedef float  f32x4  __attribute__((ext_vector_type(4)));

__device__ inline unsigned short f2bf(float f) {
    unsigned int u = __float_as_uint(f);
    u += 0x7fffu + ((u >> 16) & 1u);
    return (unsigned short)(u >> 16);
}

// ---- pre-pass 1: K fp32 [b][s][kvh][d] -> bf16 kc [b][kvh][s][d] ----
__global__ void kconv_kernel(const float* __restrict__ k, unsigned short* __restrict__ kc) {
    const size_t i = ((size_t)blockIdx.x * 256 + threadIdx.x) * 4;
    const int    d   = (int)(i & (D_ - 1));
    const size_t t1  = i >> 7;            // (b*S+s)*KVH + kvh
    const int    kvh = (int)(t1 & (KVH_ - 1));
    const size_t t2  = t1 >> 3;           // b*S+s
    const int    s   = (int)(t2 & (S_ - 1));
    const int    b   = (int)(t2 >> 11);
    const float4 x = *(const float4*)(k + i);
    ushort4 w;
    w.x = f2bf(x.x); w.y = f2bf(x.y); w.z = f2bf(x.z); w.w = f2bf(x.w);
    *(ushort4*)(kc + ((size_t)(b * KVH_ + kvh) * S_ + s) * D_ + d) = w;
}

// ---- pre-pass 2: V fp32 [b][s][kvh][d] -> bf16 vt blocked-transposed [bkvh][kt][d][KB] ----
__global__ void vtrans_kernel(const float* __restrict__ v, unsigned short* __restrict__ vt) {
    __shared__ unsigned short tile[32][33];
    const int r = threadIdx.x >> 5, c = threadIdx.x & 31;
    const int s0 = blockIdx.x * 32, d0 = blockIdx.y * 32;
    const int b = blockIdx.z >> 3, kvh = blockIdx.z & 7;
    #pragma unroll
    for (int i = 0; i < 4; ++i) {
        const int s = s0 + r + i * 8;
        tile[c][r + i * 8] =
            f2bf(v[((size_t)(b * S_ + s)) * (KVH_ * D_) + kvh * D_ + d0 + c]);
    }
    __syncthreads();
    const int s_abs = s0 + c;
    const int kt = s_abs >> 6, ks = s_abs & 63;
    #pragma unroll
    for (int i = 0; i < 4; ++i) {
        const int dd = d0 + r + i * 8;
        vt[((size_t)(b * KVH_ + kvh) * NT_ + kt) * (D_ * KB) + dd * KB + ks] =
            tile[r + i * 8][c];
    }
}

// ---- async 16B global->LDS DMA (wave-uniform LDS base + lane*16) ----
__device__ inline void gload_lds16(const void* g, void* l) {
    __builtin_amdgcn_global_load_lds(
        (const __attribute__((address_space(1))) unsigned int*)g,
        (__attribute__((address_space(3))) unsigned int*)l, 16, 0, 0);
}

// ---- main flash kernel ----
// LDS: Ksh[2][64*128] (2x16KB), Vsh[2][128*64] (2x16KB), Psh[64*72] (9KB) = 74.7KB
// K/V tiles DMA'd with XOR-swizzle on the SOURCE chunk index: LDS slot s of row r
// holds global chunk s^(r&7) -> unpadded DMA layout, conflict-free b128 frag reads.
__global__ __launch_bounds__(256, 2) void fa3_kernel(
    const float* __restrict__ q, const unsigned short* __restrict__ kc,
    const unsigned short* __restrict__ vt, float* __restrict__ out) {

#define P_STRIDE 72
    __shared__ unsigned short Ksh[2][QB * D_];
    __shared__ unsigned short Vsh[2][D_ * KB];
    __shared__ unsigned short Psh[QB * P_STRIDE];

    const int t    = threadIdx.x;
    const int wave = t >> 6;
    const int lane = t & 63;
    const int m16  = lane & 15;
    const int quad = lane >> 4;
    const int sw   = m16 & 7;          // fragment-read swizzle key

    const int qt  = (S_ / QB - 1) - blockIdx.x;  // heavy tiles first
    const int bh  = blockIdx.y;
    const int b   = bh / H_;
    const int h   = bh % H_;
    const int kvh = h / NREP;
    const int qbase = qt * QB;

    // ---- Q A-fragments direct from global fp32 (once) ----
    short8 qf[4];
    {
        const float* qp = q + (size_t)(b * S_ + qbase + wave * 16 + m16) * (H_ * D_) + h * D_;
        #pragma unroll
        for (int c = 0; c < 4; ++c) {
            const float4 x0 = *(const float4*)(qp + c * 32 + quad * 8);
            const float4 x1 = *(const float4*)(qp + c * 32 + quad * 8 + 4);
            short8 f;
            f[0] = (short)f2bf(x0.x); f[1] = (short)f2bf(x0.y);
            f[2] = (short)f2bf(x0.z); f[3] = (short)f2bf(x0.w);
            f[4] = (short)f2bf(x1.x); f[5] = (short)f2bf(x1.y);
            f[6] = (short)f2bf(x1.z); f[7] = (short)f2bf(x1.w);
            qf[c] = f;
        }
    }

    const unsigned short* kbase = kc + (size_t)(b * KVH_ + kvh) * S_ * D_;
    const unsigned short* vbase = vt + (size_t)(b * KVH_ + kvh) * NT_ * (D_ * KB);

    // staging lane geometry (precomputed)
    const int krow0 = lane >> 4, kslot = lane & 15;   // K: 4 rows/instr (256B rows)
    const int vrow0 = lane >> 3, vslot = lane & 7;    // V: 8 rows/instr (128B rows)

    // ---- stage tile 0 into buffer 0 ----
    {
        const char* kt0 = (const char*)kbase;                   // kb = 0
        const char* vt0 = (const char*)vbase;                   // kt = 0
        #pragma unroll
        for (int i = 0; i < 4; ++i) {
            const int r = wave * 16 + i * 4 + krow0;
            gload_lds16(kt0 + (size_t)r * 256 + ((kslot ^ (r & 7)) << 4),
                        &Ksh[0][(wave * 16 + i * 4) * 128]);
        }
        #pragma unroll
        for (int i = 0; i < 4; ++i) {
            const int r = wave * 32 + i * 8 + vrow0;
            gload_lds16(vt0 + (size_t)r * 128 + ((vslot ^ (r & 7)) << 4),
                        &Vsh[0][(wave * 32 + i * 8) * 64]);
        }
    }

    f32x4 o[8];
    #pragma unroll
    for (int i = 0; i < 8; ++i) o[i] = (f32x4){0.f, 0.f, 0.f, 0.f};
    float m_i[4], l_i[4];
    #pragma unroll
    for (int r = 0; r < 4; ++r) { m_i[r] = -INFINITY; l_i[r] = 0.f; }

    for (int kt = 0; kt <= qt; ++kt) {
        const int bf = kt & 1;
        __syncthreads();   // vmcnt(0) drain: tile kt staged & visible to all waves

        // ---- prefetch tile kt+1 into the other buffer (async) ----
        if (kt < qt) {
            const char* ktg = (const char*)(kbase + (size_t)(kt + 1) * KB * D_);
            const char* vtg = (const char*)(vbase + (size_t)(kt + 1) * (D_ * KB));
            #pragma unroll
            for (int i = 0; i < 4; ++i) {
                const int r = wave * 16 + i * 4 + krow0;
                gload_lds16(ktg + (size_t)r * 256 + ((kslot ^ (r & 7)) << 4),
                            &Ksh[bf ^ 1][(wave * 16 + i * 4) * 128]);
            }
            #pragma unroll
            for (int i = 0; i < 4; ++i) {
                const int r = wave * 32 + i * 8 + vrow0;
                gload_lds16(vtg + (size_t)r * 128 + ((vslot ^ (r & 7)) << 4),
                            &Vsh[bf ^ 1][(wave * 32 + i * 8) * 64]);
            }
        }

        const unsigned short* Kb = Ksh[bf];
        const unsigned short* Vb = Vsh[bf];
        const int kb = kt * KB;

        // ---- S = Q K^T: B-frags from swizzled LDS ----
        f32x4 sa[4];
        #pragma unroll
        for (int nt = 0; nt < 4; ++nt) sa[nt] = (f32x4){0.f, 0.f, 0.f, 0.f};
        #pragma unroll
        for (int c = 0; c < 4; ++c) {
            short8 kf[4];
            #pragma unroll
            for (int nt = 0; nt < 4; ++nt) {
                const int r = nt * 16 + m16;
                kf[nt] = *(const short8*)
                    ((const char*)Kb + r * 256 + (((c * 4 + quad) ^ sw) << 4));
            }
            #pragma unroll
            for (int nt = 0; nt < 4; ++nt)
                sa[nt] = __builtin_amdgcn_mfma_f32_16x16x32_bf16(qf[c], kf[nt], sa[nt], 0, 0, 0);
        }

        // ---- scale + causal mask ----
        const bool diag = (kt == qt);
        float p[4][4];
        #pragma unroll
        for (int nt = 0; nt < 4; ++nt) {
            #pragma unroll
            for (int r = 0; r < 4; ++r) {
                float sv = sa[nt][r] * SCALE;
                if (diag) {
                    const int rowg = qbase + wave * 16 + quad * 4 + r;
                    const int colg = kb + nt * 16 + m16;
                    if (colg > rowg) sv = -INFINITY;
                }
                p[nt][r] = sv;
            }
        }

        // ---- online softmax across the quad-row's 16 lanes ----
        float alpha[4];
        #pragma unroll
        for (int r = 0; r < 4; ++r) {
            float mv = fmaxf(fmaxf(p[0][r], p[1][r]), fmaxf(p[2][r], p[3][r]));
            mv = fmaxf(mv, __shfl_xor(mv, 1));
            mv = fmaxf(mv, __shfl_xor(mv, 2));
            mv = fmaxf(mv, __shfl_xor(mv, 4));
            mv = fmaxf(mv, __shfl_xor(mv, 8));
            const float mnew = fmaxf(m_i[r], mv);
            alpha[r] = __expf(m_i[r] - mnew);
            m_i[r] = mnew;
            float rs = 0.f;
            #pragma unroll
            for (int nt = 0; nt < 4; ++nt) {
                const float e = __expf(p[nt][r] - mnew);
                p[nt][r] = e;
                rs += e;
            }
            rs += __shfl_xor(rs, 1);
            rs += __shfl_xor(rs, 2);
            rs += __shfl_xor(rs, 4);
            rs += __shfl_xor(rs, 8);
            l_i[r] = l_i[r] * alpha[r] + rs;
        }

        // ---- P: C-layout -> LDS (wave-private rows) ----
        #pragma unroll
        for (int nt = 0; nt < 4; ++nt)
            #pragma unroll
            for (int r = 0; r < 4; ++r)
                Psh[(wave * 16 + quad * 4 + r) * P_STRIDE + nt * 16 + m16] = f2bf(p[nt][r]);

        #pragma unroll
        for (int dn = 0; dn < 8; ++dn)
            #pragma unroll
            for (int r = 0; r < 4; ++r)
                o[dn][r] *= alpha[r];

        asm volatile("s_waitcnt lgkmcnt(0)" ::: "memory");
        const short8 pf0 = *(const short8*)&Psh[(wave * 16 + m16) * P_STRIDE + quad * 8];
        const short8 pf1 = *(const short8*)&Psh[(wave * 16 + m16) * P_STRIDE + 32 + quad * 8];

        // ---- O += P V: B-frags from swizzled LDS ----
        #pragma unroll
        for (int c2 = 0; c2 < 2; ++c2) {
            const short8 pf = c2 ? pf1 : pf0;
            #pragma unroll
            for (int dn = 0; dn < 8; ++dn) {
                const int d = dn * 16 + m16;
                const short8 vf = *(const short8*)
                    ((const char*)Vb + d * 128 + (((c2 * 4 + quad) ^ sw) << 4));
                o[dn] = __builtin_amdgcn_mfma_f32_16x16x32_bf16(pf, vf, o[dn], 0, 0, 0);
            }
        }
    }

    // ---- epilogue: normalize, transpose O through LDS, float4 coalesced stores ----
    float inv[4];
    #pragma unroll
    for (int r = 0; r < 4; ++r) inv[r] = 1.f / l_i[r];

    __syncthreads();  // everyone done reading Vsh; reuse it as fp32 O-tile
    float* Ot = (float*)&Vsh[0][0] + wave * (16 * 128);   // [16][128] per wave
    #pragma unroll
    for (int dn = 0; dn < 8; ++dn)
        #pragma unroll
        for (int r = 0; r < 4; ++r)
            Ot[(quad * 4 + r) * 128 + dn * 16 + m16] = o[dn][r] * inv[r];

    asm volatile("s_waitcnt lgkmcnt(0)" ::: "memory");
    float* og = out + (size_t)(b * S_ + qbase + wave * 16) * (H_ * D_) + h * D_;
    #pragma unroll
    for (int i = 0; i < 8; ++i) {
        const int row = (lane >> 5) + i * 2;
        const int col = (lane & 31) * 4;
        *(float4*)(og + (size_t)row * (H_ * D_) + col) = *(const float4*)(Ot + row * 128 + col);
    }
#undef P_STRIDE
}

extern "C" void kernel_launch(void* const* d_in, const int* in_sizes, int n_in,
                              void* d_out, int out_size, void* d_ws, size_t ws_size,
                              hipStream_t stream) {
    const float* q = (const float*)d_in[0];
    const float* k = (const float*)d_in[1];
    const float* v = (const float*)d_in[2];
    float* out = (float*)d_out;

    unsigned short* kc = (unsigned short*)d_ws;                                   // 8.4 MB
    unsigned short* vt = (unsigned short*)d_ws + (size_t)B_ * KVH_ * S_ * D_;     // 8.4 MB

    kconv_kernel<<<dim3(4096), dim3(256), 0, stream>>>(k, kc);
    vtrans_kernel<<<dim3(S_ / 32, D_ / 32, B_ * KVH_), dim3(256), 0, stream>>>(v, vt);
    fa3_kernel<<<dim3(S_ / QB, B_ * H_), dim3(256), 0, stream>>>(q, kc, vt, out);
}